// Round 1
// baseline (192.248 us; speedup 1.0000x reference)
//
#include <hip/hip_runtime.h>
#include <cstdint>

#define HH 512
#define WW 512
#define NBATCH 16
#define NPRED 4
#define NSLICE 64
#define WPR 8                       // 64-bit words per row (512 bits)
#define NELEM (NBATCH*NPRED*HH*WW)  // 16,777,216

// ---- helpers ---------------------------------------------------------------

static __device__ __forceinline__ uint64_t ldw(const uint64_t* __restrict__ b,
                                               int s, int r, int c) {
    if ((unsigned)r >= (unsigned)HH || (unsigned)c >= (unsigned)WPR) return 0ULL;
    return b[((size_t)s*HH + r)*WPR + c];
}

// full adder on bit-planes
static __device__ __forceinline__ void fadd(uint64_t a, uint64_t b, uint64_t ci,
                                            uint64_t& s, uint64_t& co) {
    uint64_t x = a ^ b;
    s  = x ^ ci;
    co = (a & b) | (ci & x);
}

// sum of 8 one-bit planes -> 4-bit bit-sliced result (b0..b3 = 1,2,4,8)
static __device__ __forceinline__ void sum8(const uint64_t q[8],
                                            uint64_t& b0, uint64_t& b1,
                                            uint64_t& b2, uint64_t& b3) {
    uint64_t s0,c0,s1,c1,s2,c2;
    fadd(q[0],q[1],q[2], s0,c0);
    fadd(q[3],q[4],q[5], s1,c1);
    s2 = q[6] ^ q[7]; c2 = q[6] & q[7];
    uint64_t ca; fadd(s0,s1,s2, b0, ca);      // ones, carry->2
    uint64_t t, cb; fadd(c0,c1,c2, t, cb);    // weight-2 sum, carry->4
    b1 = t ^ ca; uint64_t cc = t & ca;        // twos, carry->4
    b2 = cb ^ cc; b3 = cb & cc;               // fours, eights
}

// load 3x3 word neighborhood and build the 8 shifted neighbor masks p2..p9
// (bit j of word (s,r,c) = pixel (r, c*64+j)); zero-padded at borders.
#define LOAD_NB(in, s, r, c)                                                   \
    uint64_t uc = ldw(in,s,(r)-1,c), up = ldw(in,s,(r)-1,(c)-1), un = ldw(in,s,(r)-1,(c)+1); \
    uint64_t mc = ldw(in,s,(r)  ,c), mp = ldw(in,s,(r)  ,(c)-1), mn = ldw(in,s,(r)  ,(c)+1); \
    uint64_t dc = ldw(in,s,(r)+1,c), dp = ldw(in,s,(r)+1,(c)-1), dn = ldw(in,s,(r)+1,(c)+1); \
    uint64_t p2 = uc;                                                          \
    uint64_t p3 = (uc >> 1) | (un << 63);                                      \
    uint64_t p4 = (mc >> 1) | (mn << 63);                                      \
    uint64_t p5 = (dc >> 1) | (dn << 63);                                      \
    uint64_t p6 = dc;                                                          \
    uint64_t p7 = (dc << 1) | (dp >> 63);                                      \
    uint64_t p8 = (mc << 1) | (mp >> 63);                                      \
    uint64_t p9 = (uc << 1) | (up >> 63);

// ---- kernels ----------------------------------------------------------------

// softmax over b (axis 0), threshold 0.5, pack bits: one thread per (p,h,w)
__global__ void k_binarize(const float* __restrict__ x, uint64_t* __restrict__ pack) {
    int tid = blockIdx.x * blockDim.x + threadIdx.x;   // 4*512*512 threads
    int w = tid & (WW-1);
    int h = (tid >> 9) & (HH-1);
    int p = tid >> 18;
    int lane = threadIdx.x & 63;
    float v[NBATCH], e[NBATCH];
    float m = -3.4e38f;
    int base = (p*HH + h)*WW + w;
    #pragma unroll
    for (int b = 0; b < NBATCH; ++b) {
        v[b] = x[(size_t)b*(NPRED*HH*WW) + base];
        m = fmaxf(m, v[b]);
    }
    float S = 0.f;
    #pragma unroll
    for (int b = 0; b < NBATCH; ++b) { e[b] = expf(v[b] - m); S += e[b]; }
    float hS = 0.5f * S;
    unsigned long long mymask = 0ULL;
    #pragma unroll
    for (int b = 0; b < NBATCH; ++b) {
        unsigned long long mk = __ballot(e[b] >= hS);
        if (lane == b) mymask = mk;
    }
    if (lane < NBATCH) {
        int slice = lane * NPRED + p;                  // A.reshape(B*Np,...) -> b*Np+p
        pack[((size_t)slice*HH + h)*WPR + (w >> 6)] = mymask;
    }
}

// one Zhang-Suen sub-iteration, bit-sliced; one thread per 64-pixel word
__global__ void k_thin(const uint64_t* __restrict__ in, uint64_t* __restrict__ out, int sub) {
    int tid = blockIdx.x * blockDim.x + threadIdx.x;   // 64*512*8 threads
    int c = tid & (WPR-1);
    int r = (tid >> 3) & (HH-1);
    int s = tid >> 12;
    LOAD_NB(in, s, r, c);

    uint64_t q[8] = {p2,p3,p4,p5,p6,p7,p8,p9};
    uint64_t n0,n1,n2,n3; sum8(q, n0,n1,n2,n3);        // Bn
    uint64_t ge2 = n1 | n2 | n3;
    uint64_t le6 = ~(n3 | (n2 & n1 & n0));
    uint64_t condB = ge2 & le6;

    uint64_t tq[8];
    #pragma unroll
    for (int i = 0; i < 8; ++i) tq[i] = ~q[i] & q[(i+1)&7];
    uint64_t t0,t1,t2,t3; sum8(tq, t0,t1,t2,t3);       // transition count
    uint64_t trans1 = t0 & ~(t1 | t2 | t3);

    uint64_t cond2;
    if (sub == 0) cond2 = ~(p2 & p4 & p6) & ~(p4 & p6 & p8);
    else          cond2 = ~(p2 & p4 & p8) & ~(p2 & p6 & p8);

    uint64_t del = mc & condB & trans1 & cond2;
    out[((size_t)s*HH + r)*WPR + c] = mc & ~del;
}

// endpoint map: all 8 neighbors set (3x3 ones-minus-center conv >= 8)
__global__ void k_endpoint(const uint64_t* __restrict__ in, uint64_t* __restrict__ cbits) {
    int tid = blockIdx.x * blockDim.x + threadIdx.x;
    int c = tid & (WPR-1);
    int r = (tid >> 3) & (HH-1);
    int s = tid >> 12;
    LOAD_NB(in, s, r, c);
    (void)mc;
    cbits[((size_t)s*HH + r)*WPR + c] = p2 & p3 & p4 & p5 & p6 & p7 & p8 & p9;
}

// vertical 9-row sums of C bits -> uint8 per pixel
__global__ void k_vsum(const uint64_t* __restrict__ cbits, uint8_t* __restrict__ v8) {
    int tid = blockIdx.x * blockDim.x + threadIdx.x;
    int c = tid & (WPR-1);
    int r = (tid >> 3) & (HH-1);
    int s = tid >> 12;
    uint64_t rows[9];
    #pragma unroll
    for (int d = 0; d < 9; ++d) rows[d] = ldw(cbits, s, r + d - 4, c);
    uint64_t s0,c0,s1,c1,s2,c2;
    fadd(rows[0],rows[1],rows[2], s0,c0);
    fadd(rows[3],rows[4],rows[5], s1,c1);
    fadd(rows[6],rows[7],rows[8], s2,c2);
    uint64_t b0, ca; fadd(s0,s1,s2, b0, ca);
    uint64_t t, cb; fadd(c0,c1,c2, t, cb);
    uint64_t b1 = t ^ ca; uint64_t cc = t & ca;
    uint64_t b2 = cb ^ cc, b3 = cb & cc;               // value 0..9

    uint64_t* out = (uint64_t*)(v8 + ((size_t)(s*HH + r)*WW + c*64));
    #pragma unroll
    for (int k = 0; k < 8; ++k) {
        uint64_t ow = 0;
        #pragma unroll
        for (int e = 0; e < 8; ++e) {
            int j = k*8 + e;
            uint64_t bv = ((b0>>j)&1ULL) | (((b1>>j)&1ULL)<<1)
                        | (((b2>>j)&1ULL)<<2) | (((b3>>j)&1ULL)<<3);
            ow |= bv << (8*e);
        }
        out[k] = ow;
    }
}

// fused: BCE loss * 60*(9x9 neighbor count of C) -> per-block double partials
__global__ void k_final(const float* __restrict__ x, const float* __restrict__ y,
                        const uint8_t* __restrict__ v8, const uint64_t* __restrict__ cbits,
                        double* __restrict__ partials) {
    int tid = blockIdx.x * blockDim.x + threadIdx.x;
    int stride = gridDim.x * blockDim.x;
    double acc = 0.0;
    for (int idx = tid; idx < NELEM; idx += stride) {
        int w  = idx & (WW-1);
        int h  = (idx >> 9) & (HH-1);
        int sl = idx >> 18;                            // == b*4+p
        float lx = x[idx], ly = y[idx];
        float loss = fmaxf(lx, 0.f) - lx*ly + log1pf(expf(-fabsf(lx)));
        size_t rowbase = (size_t)sl*HH + h;
        const uint8_t* vp = v8 + rowbase*WW;
        int lo = (w-4 < 0) ? 0 : w-4;
        int hi = (w+4 > WW-1) ? WW-1 : w+4;
        int sum = 0;
        for (int ww = lo; ww <= hi; ++ww) sum += vp[ww];
        int cb = (int)((cbits[rowbase*WPR + (w>>6)] >> (w & 63)) & 1ULL);
        float wmap = 60.f * (float)(sum - cb);
        acc += (double)(loss * wmap);
    }
    __shared__ double sdata[256];
    sdata[threadIdx.x] = acc;
    __syncthreads();
    for (int s2 = 128; s2 > 0; s2 >>= 1) {
        if (threadIdx.x < s2) sdata[threadIdx.x] += sdata[threadIdx.x + s2];
        __syncthreads();
    }
    if (threadIdx.x == 0) partials[blockIdx.x] = sdata[0];
}

__global__ void k_reduce(const double* __restrict__ partials, float* __restrict__ out,
                         int nparts) {
    __shared__ double sdata[256];
    double a = 0.0;
    for (int i = threadIdx.x; i < nparts; i += 256) a += partials[i];
    sdata[threadIdx.x] = a;
    __syncthreads();
    for (int s2 = 128; s2 > 0; s2 >>= 1) {
        if (threadIdx.x < s2) sdata[threadIdx.x] += sdata[threadIdx.x + s2];
        __syncthreads();
    }
    if (threadIdx.x == 0) out[0] = (float)(sdata[0] / (double)NELEM);
}

// ---- launch ------------------------------------------------------------------

extern "C" void kernel_launch(void* const* d_in, const int* in_sizes, int n_in,
                              void* d_out, int out_size, void* d_ws, size_t ws_size,
                              hipStream_t stream) {
    const float* x = (const float*)d_in[0];
    const float* y = (const float*)d_in[1];
    char* ws = (char*)d_ws;
    uint64_t* packA   = (uint64_t*)(ws);                       // 2 MB
    uint64_t* packB   = (uint64_t*)(ws + (2u<<20));            // 2 MB
    uint64_t* cbits   = (uint64_t*)(ws + (4u<<20));            // 2 MB
    uint8_t*  v8      = (uint8_t*) (ws + (6u<<20));            // 16 MB
    double*   partials= (double*)  (ws + (22u<<20));           // 16 KB

    k_binarize<<<4096, 256, 0, stream>>>(x, packA);
    for (int it = 0; it < 8; ++it) {
        k_thin<<<1024, 256, 0, stream>>>(packA, packB, 0);
        k_thin<<<1024, 256, 0, stream>>>(packB, packA, 1);
    }
    k_endpoint<<<1024, 256, 0, stream>>>(packA, cbits);
    k_vsum<<<1024, 256, 0, stream>>>(cbits, v8);
    k_final<<<2048, 256, 0, stream>>>(x, y, v8, cbits, partials);
    k_reduce<<<1, 256, 0, stream>>>(partials, (float*)d_out, 2048);
}

// Round 2
// 131.154 us; speedup vs baseline: 1.4658x; 1.4658x over previous
//
#include <hip/hip_runtime.h>
#include <cstdint>

#define HH 512
#define WW 512
#define NBATCH 16
#define NPRED 4
#define WPR 8                        // 64-bit words per row
#define NELEM (NBATCH*NPRED*HH*WW)   // 16,777,216
#define NRTOT 170                    // LDS rows per block (128 + 2*21 halo)
#define HALO 21
#define LP (WPR+2)                   // padded LDS row stride (zero border cols)
#define PLANE ((size_t)64*HH*WPR)    // uint64 words per weight bit-plane

// ---- bit-sliced helpers -----------------------------------------------------

static __device__ __forceinline__ void fadd(uint64_t a, uint64_t b, uint64_t ci,
                                            uint64_t& s, uint64_t& co) {
    uint64_t x = a ^ b;
    s  = x ^ ci;
    co = (a & b) | (ci & x);
}

// in-place full add: a = (a + b + c) low bit, c = carry
static __device__ __forceinline__ void faddio(uint64_t& a, uint64_t b, uint64_t& c) {
    uint64_t x = a ^ b;
    uint64_t s = x ^ c;
    c = (a & b) | (c & x);
    a = s;
}

// sum of 8 one-bit planes -> 4-bit bit-sliced (b0..b3 = 1,2,4,8)
static __device__ __forceinline__ void sum8(const uint64_t q[8],
                                            uint64_t& b0, uint64_t& b1,
                                            uint64_t& b2, uint64_t& b3) {
    uint64_t s0,c0,s1,c1,s2,c2;
    fadd(q[0],q[1],q[2], s0,c0);
    fadd(q[3],q[4],q[5], s1,c1);
    s2 = q[6] ^ q[7]; c2 = q[6] & q[7];
    uint64_t ca; fadd(s0,s1,s2, b0, ca);
    uint64_t t, cb; fadd(c0,c1,c2, t, cb);
    b1 = t ^ ca; uint64_t cc = t & ca;
    b2 = cb ^ cc; b3 = cb & cc;
}

// w[0..6] += 4-bit number (b0..b3); max value 81, no overflow past bit 6
static __device__ __forceinline__ void acc74(uint64_t w[7], uint64_t b0, uint64_t b1,
                                             uint64_t b2, uint64_t b3) {
    uint64_t c;
    { uint64_t x = w[0] ^ b0; c = w[0] & b0; w[0] = x; }
    faddio(w[1], b1, c);
    faddio(w[2], b2, c);
    faddio(w[3], b3, c);
    { uint64_t x = w[4] ^ c; c = w[4] & c; w[4] = x; }
    { uint64_t x = w[5] ^ c; c = w[5] & c; w[5] = x; }
    w[6] ^= c;
}

// ---- kernels ----------------------------------------------------------------

// softmax over batch axis, threshold 0.5, pack bits (one thread per (p,h,w))
__global__ void k_binarize(const float* __restrict__ x, uint64_t* __restrict__ pack) {
    int tid = blockIdx.x * blockDim.x + threadIdx.x;   // 4*512*512 threads
    int w = tid & (WW-1);
    int h = (tid >> 9) & (HH-1);
    int p = tid >> 18;
    int lane = threadIdx.x & 63;
    float v[NBATCH], e[NBATCH];
    float m = -3.4e38f;
    int base = (p*HH + h)*WW + w;
    #pragma unroll
    for (int b = 0; b < NBATCH; ++b) {
        v[b] = x[(size_t)b*(NPRED*HH*WW) + base];
        m = fmaxf(m, v[b]);
    }
    float S = 0.f;
    #pragma unroll
    for (int b = 0; b < NBATCH; ++b) { e[b] = expf(v[b] - m); S += e[b]; }
    float hS = 0.5f * S;
    unsigned long long mymask = 0ULL;
    #pragma unroll
    for (int b = 0; b < NBATCH; ++b) {
        unsigned long long mk = __ballot(e[b] >= hS);
        if (lane == b) mymask = mk;
    }
    if (lane < NBATCH) {
        int slice = lane * NPRED + p;                  // b*Np + p
        pack[((size_t)slice*HH + h)*WPR + (w >> 6)] = mymask;
    }
}

// fused: 16 Zhang-Suen substeps + endpoint C + 9x9-minus-center sum (7 bit-planes)
// 4 blocks per slice (128 output rows each), all state in LDS.
__global__ __launch_bounds__(512) void k_thin_wmap(const uint64_t* __restrict__ pack,
                                                   uint64_t* __restrict__ wp) {
    __shared__ uint64_t A[(NRTOT+2)*LP];
    __shared__ uint64_t B[(NRTOT+2)*LP];
    __shared__ uint64_t Hs[4*136*WPR];                 // horizontal-sum planes
    const int s    = blockIdx.x >> 2;
    const int base = (blockIdx.x & 3) << 7;
    const int R0   = base - HALO;
    const int tid  = threadIdx.x;

    for (int i = tid; i < (NRTOT+2)*LP; i += 512) { A[i] = 0; B[i] = 0; }
    __syncthreads();
    for (int i = tid; i < NRTOT*WPR; i += 512) {
        int lr = i >> 3, c = i & 7;
        int r = R0 + lr;
        if ((unsigned)r < (unsigned)HH)
            A[(lr+1)*LP + c + 1] = pack[((size_t)s*HH + r)*WPR + c];
    }
    __syncthreads();

    uint64_t* cur = A; uint64_t* nxt = B;
    for (int step = 0; step < 16; ++step) {
        for (int i = tid; i < NRTOT*WPR; i += 512) {
            int lr = i >> 3, c = i & 7;
            int o = (lr+1)*LP + c + 1;
            uint64_t up = cur[o-LP-1], uc = cur[o-LP], un = cur[o-LP+1];
            uint64_t mp = cur[o-1],    mc = cur[o],    mn = cur[o+1];
            uint64_t dp = cur[o+LP-1], dc = cur[o+LP], dn = cur[o+LP+1];
            uint64_t p2 = uc;
            uint64_t p3 = (uc>>1)|(un<<63);
            uint64_t p4 = (mc>>1)|(mn<<63);
            uint64_t p5 = (dc>>1)|(dn<<63);
            uint64_t p6 = dc;
            uint64_t p7 = (dc<<1)|(dp>>63);
            uint64_t p8 = (mc<<1)|(mp>>63);
            uint64_t p9 = (uc<<1)|(up>>63);
            uint64_t qq[8] = {p2,p3,p4,p5,p6,p7,p8,p9};
            uint64_t n0,n1,n2,n3; sum8(qq,n0,n1,n2,n3);
            uint64_t condB = (n1|n2|n3) & ~(n3 | (n2&n1&n0));
            uint64_t tq[8];
            #pragma unroll
            for (int k = 0; k < 8; ++k) tq[k] = ~qq[k] & qq[(k+1)&7];
            uint64_t t0,t1,t2,t3; sum8(tq,t0,t1,t2,t3);
            uint64_t trans1 = t0 & ~(t1|t2|t3);
            uint64_t cond2 = (step & 1) ? (~(p2&p4&p8) & ~(p2&p6&p8))
                                        : (~(p2&p4&p6) & ~(p4&p6&p8));
            nxt[o] = mc & ~(condB & trans1 & cond2);
        }
        __syncthreads();
        uint64_t* t = cur; cur = nxt; nxt = t;
    }
    // cur == A (16 swaps). Endpoint C (all 8 neighbors set) into B, rows lr 16..153.
    for (int i = tid; i < 138*WPR; i += 512) {
        int lr = (i >> 3) + 16, c = i & 7;
        int o = (lr+1)*LP + c + 1;
        uint64_t up = cur[o-LP-1], uc = cur[o-LP], un = cur[o-LP+1];
        uint64_t mp = cur[o-1],                    mn = cur[o+1];
        uint64_t dp = cur[o+LP-1], dc = cur[o+LP], dn = cur[o+LP+1];
        uint64_t p3 = (uc>>1)|(un<<63);
        uint64_t p4 = (mn<<63)|(cur[o]>>1);
        uint64_t mc = cur[o];
        p4 = (mc>>1)|(mn<<63);
        uint64_t p5 = (dc>>1)|(dn<<63);
        uint64_t p7 = (dc<<1)|(dp>>63);
        uint64_t p8 = (mc<<1)|(mp>>63);
        uint64_t p9 = (uc<<1)|(up>>63);
        B[o] = uc & p3 & p4 & p5 & dc & p7 & p8 & p9;
    }
    __syncthreads();
    // Phase A: horizontal 9-window sums (center included) -> 4 bit-planes,
    // rows lr 17..152 (hr 0..135)
    for (int i = tid; i < 136*WPR; i += 512) {
        int hr = i >> 3, c = i & 7;
        int o = (hr+18)*LP + c + 1;                    // lr = hr+17
        uint64_t mp = B[o-1], mc = B[o], mn = B[o+1];
        uint64_t m[8];
        m[0] = (mc>>1)|(mn<<63); m[1] = (mc>>2)|(mn<<62);
        m[2] = (mc>>3)|(mn<<61); m[3] = (mc>>4)|(mn<<60);
        m[4] = (mc<<1)|(mp>>63); m[5] = (mc<<2)|(mp>>62);
        m[6] = (mc<<3)|(mp>>61); m[7] = (mc<<4)|(mp>>60);
        uint64_t b0,b1,b2,b3; sum8(m,b0,b1,b2,b3);
        // + center (ripple increment, max 9)
        uint64_t inc = mc;
        uint64_t s0 = b0 ^ inc; inc &= b0;
        uint64_t s1 = b1 ^ inc; inc &= b1;
        uint64_t s2 = b2 ^ inc; inc &= b2;
        uint64_t s3 = b3 ^ inc;
        Hs[0*1088 + i] = s0; Hs[1*1088 + i] = s1;
        Hs[2*1088 + i] = s2; Hs[3*1088 + i] = s3;
    }
    __syncthreads();
    // Phase B: vertical 9-row sums of H -> 7 bit-planes, minus center C bit.
    for (int i = tid; i < 128*WPR; i += 512) {
        int orr = i >> 3, c = i & 7;
        uint64_t w[7];
        int h0 = orr*WPR + c;
        w[0] = Hs[0*1088 + h0]; w[1] = Hs[1*1088 + h0];
        w[2] = Hs[2*1088 + h0]; w[3] = Hs[3*1088 + h0];
        w[4] = 0; w[5] = 0; w[6] = 0;
        #pragma unroll
        for (int d = 1; d < 9; ++d) {
            int hh = (orr+d)*WPR + c;
            acc74(w, Hs[0*1088+hh], Hs[1*1088+hh], Hs[2*1088+hh], Hs[3*1088+hh]);
        }
        // subtract center C bit (borrow ripple; sum>=1 when C set, no underflow)
        uint64_t cb = B[(orr+HALO+1)*LP + c + 1];
        #pragma unroll
        for (int j = 0; j < 7; ++j) {
            uint64_t t = w[j];
            w[j] = t ^ cb;
            cb &= ~t;
        }
        size_t widx = ((size_t)s*HH + base + orr)*WPR + c;
        #pragma unroll
        for (int j = 0; j < 7; ++j) wp[j*PLANE + widx] = w[j];
    }
}

// fused: BCE loss * 60*W (reconstructed from 7 bit-planes) -> double partials
__global__ __launch_bounds__(256) void k_final(const float* __restrict__ x,
                        const float* __restrict__ y,
                        const uint64_t* __restrict__ wp,
                        double* __restrict__ partials) {
    int tid = blockIdx.x * blockDim.x + threadIdx.x;
    int stride = gridDim.x * blockDim.x;
    double acc = 0.0;
    for (int j4 = tid; j4 < NELEM/4; j4 += stride) {
        int idx = j4 << 2;
        int wpx = idx & (WW-1);
        int h   = (idx >> 9) & (HH-1);
        int sl  = idx >> 18;
        size_t widx = ((size_t)sl*HH + h)*WPR + (wpx >> 6);
        int bit = wpx & 63;
        uint32_t bytes = 0;                            // 4 packed counts (<=81)
        #pragma unroll
        for (int j = 0; j < 7; ++j) {
            uint32_t nib = (uint32_t)(wp[j*PLANE + widx] >> bit) & 0xFu;
            uint32_t t = (nib | (nib << 14)) & 0x00030003u;
            t = (t | (t << 7)) & 0x01010101u;          // spread 4 bits -> 4 bytes
            bytes += t << j;
        }
        const float4 xv = *reinterpret_cast<const float4*>(x + idx);
        const float4 yv = *reinterpret_cast<const float4*>(y + idx);
        const float* xs = &xv.x; const float* ys = &yv.x;
        #pragma unroll
        for (int k = 0; k < 4; ++k) {
            float lx = xs[k], ly = ys[k];
            float loss = fmaxf(lx, 0.f) - lx*ly + log1pf(expf(-fabsf(lx)));
            float wf = (float)((bytes >> (8*k)) & 0xFFu);
            acc += (double)(loss * (60.0f * wf));
        }
    }
    __shared__ double sdata[256];
    sdata[threadIdx.x] = acc;
    __syncthreads();
    for (int s2 = 128; s2 > 0; s2 >>= 1) {
        if (threadIdx.x < s2) sdata[threadIdx.x] += sdata[threadIdx.x + s2];
        __syncthreads();
    }
    if (threadIdx.x == 0) partials[blockIdx.x] = sdata[0];
}

__global__ void k_reduce(const double* __restrict__ partials, float* __restrict__ out,
                         int nparts) {
    __shared__ double sdata[256];
    double a = 0.0;
    for (int i = threadIdx.x; i < nparts; i += 256) a += partials[i];
    sdata[threadIdx.x] = a;
    __syncthreads();
    for (int s2 = 128; s2 > 0; s2 >>= 1) {
        if (threadIdx.x < s2) sdata[threadIdx.x] += sdata[threadIdx.x + s2];
        __syncthreads();
    }
    if (threadIdx.x == 0) out[0] = (float)(sdata[0] / (double)NELEM);
}

// ---- launch ------------------------------------------------------------------

extern "C" void kernel_launch(void* const* d_in, const int* in_sizes, int n_in,
                              void* d_out, int out_size, void* d_ws, size_t ws_size,
                              hipStream_t stream) {
    const float* x = (const float*)d_in[0];
    const float* y = (const float*)d_in[1];
    char* ws = (char*)d_ws;
    uint64_t* packA    = (uint64_t*)(ws);              // 2 MB
    uint64_t* wplanes  = (uint64_t*)(ws + (2u<<20));   // 7 x 2 MB
    double*   partials = (double*)  (ws + (17u<<20));  // 16 KB

    k_binarize<<<4096, 256, 0, stream>>>(x, packA);
    k_thin_wmap<<<256, 512, 0, stream>>>(packA, wplanes);
    k_final<<<2048, 256, 0, stream>>>(x, y, wplanes, partials);
    k_reduce<<<1, 256, 0, stream>>>(partials, (float*)d_out, 2048);
}

// Round 3
// 67.077 us; speedup vs baseline: 2.8661x; 1.9553x over previous
//
#include <hip/hip_runtime.h>
#include <cstdint>

#define HH 512
#define WW 512
#define NBATCH 16
#define NPRED 4
#define WPR 8                        // 64-bit words per row
#define NELEM (NBATCH*NPRED*HH*WW)   // 16,777,216
#define NWORDS (64*HH*WPR)           // 262,144 packed words total
#define NRTOT 170                    // LDS rows per block (128 + 2*21 halo)
#define HALO 21
#define LP (WPR+2)                   // padded LDS row stride (zero border cols)
#define PLANE ((size_t)NWORDS)       // uint64 words per weight bit-plane

// ---- bit-sliced helpers -----------------------------------------------------

static __device__ __forceinline__ void fadd(uint64_t a, uint64_t b, uint64_t ci,
                                            uint64_t& s, uint64_t& co) {
    uint64_t x = a ^ b;
    s  = x ^ ci;
    co = (a & b) | (ci & x);
}

static __device__ __forceinline__ void faddio(uint64_t& a, uint64_t b, uint64_t& c) {
    uint64_t x = a ^ b;
    uint64_t s = x ^ c;
    c = (a & b) | (c & x);
    a = s;
}

static __device__ __forceinline__ void sum8(const uint64_t q[8],
                                            uint64_t& b0, uint64_t& b1,
                                            uint64_t& b2, uint64_t& b3) {
    uint64_t s0,c0,s1,c1,s2,c2;
    fadd(q[0],q[1],q[2], s0,c0);
    fadd(q[3],q[4],q[5], s1,c1);
    s2 = q[6] ^ q[7]; c2 = q[6] & q[7];
    uint64_t ca; fadd(s0,s1,s2, b0, ca);
    uint64_t t, cb; fadd(c0,c1,c2, t, cb);
    b1 = t ^ ca; uint64_t cc = t & ca;
    b2 = cb ^ cc; b3 = cb & cc;
}

// w[0..6] += 4-bit number (b0..b3); max 81, no overflow past bit 6
static __device__ __forceinline__ void acc74(uint64_t w[7], uint64_t b0, uint64_t b1,
                                             uint64_t b2, uint64_t b3) {
    uint64_t c;
    { uint64_t x = w[0] ^ b0; c = w[0] & b0; w[0] = x; }
    faddio(w[1], b1, c);
    faddio(w[2], b2, c);
    faddio(w[3], b3, c);
    { uint64_t x = w[4] ^ c; c = w[4] & c; w[4] = x; }
    { uint64_t x = w[5] ^ c; c = w[5] & c; w[5] = x; }
    w[6] ^= c;
}

// ---- kernels ----------------------------------------------------------------

// softmax over batch axis, threshold 0.5, pack bits (one thread per (p,h,w))
__global__ void k_binarize(const float* __restrict__ x, uint64_t* __restrict__ pack) {
    int tid = blockIdx.x * blockDim.x + threadIdx.x;   // 4*512*512 threads
    int w = tid & (WW-1);
    int h = (tid >> 9) & (HH-1);
    int p = tid >> 18;
    int lane = threadIdx.x & 63;
    float v[NBATCH], e[NBATCH];
    float m = -3.4e38f;
    int base = (p*HH + h)*WW + w;
    #pragma unroll
    for (int b = 0; b < NBATCH; ++b) {
        v[b] = x[(size_t)b*(NPRED*HH*WW) + base];
        m = fmaxf(m, v[b]);
    }
    float S = 0.f;
    #pragma unroll
    for (int b = 0; b < NBATCH; ++b) { e[b] = expf(v[b] - m); S += e[b]; }
    float hS = 0.5f * S;
    unsigned long long mymask = 0ULL;
    #pragma unroll
    for (int b = 0; b < NBATCH; ++b) {
        unsigned long long mk = __ballot(e[b] >= hS);
        if (lane == b) mymask = mk;
    }
    if (lane < NBATCH) {
        int slice = lane * NPRED + p;                  // b*Np + p
        pack[((size_t)slice*HH + h)*WPR + (w >> 6)] = mymask;
    }
}

// fused: 16 Zhang-Suen substeps + endpoint C + 9x9-minus-center sum (7 bit-planes)
__global__ __launch_bounds__(512) void k_thin_wmap(const uint64_t* __restrict__ pack,
                                                   uint64_t* __restrict__ wp) {
    __shared__ uint64_t A[(NRTOT+2)*LP];
    __shared__ uint64_t B[(NRTOT+2)*LP];
    __shared__ uint64_t Hs[4*136*WPR];                 // horizontal-sum planes
    const int s    = blockIdx.x >> 2;
    const int base = (blockIdx.x & 3) << 7;
    const int R0   = base - HALO;
    const int tid  = threadIdx.x;

    for (int i = tid; i < (NRTOT+2)*LP; i += 512) { A[i] = 0; B[i] = 0; }
    __syncthreads();
    for (int i = tid; i < NRTOT*WPR; i += 512) {
        int lr = i >> 3, c = i & 7;
        int r = R0 + lr;
        if ((unsigned)r < (unsigned)HH)
            A[(lr+1)*LP + c + 1] = pack[((size_t)s*HH + r)*WPR + c];
    }
    __syncthreads();

    uint64_t* cur = A; uint64_t* nxt = B;
    for (int step = 0; step < 16; ++step) {
        for (int i = tid; i < NRTOT*WPR; i += 512) {
            int lr = i >> 3, c = i & 7;
            int o = (lr+1)*LP + c + 1;
            uint64_t up = cur[o-LP-1], uc = cur[o-LP], un = cur[o-LP+1];
            uint64_t mp = cur[o-1],    mc = cur[o],    mn = cur[o+1];
            uint64_t dp = cur[o+LP-1], dc = cur[o+LP], dn = cur[o+LP+1];
            uint64_t p2 = uc;
            uint64_t p3 = (uc>>1)|(un<<63);
            uint64_t p4 = (mc>>1)|(mn<<63);
            uint64_t p5 = (dc>>1)|(dn<<63);
            uint64_t p6 = dc;
            uint64_t p7 = (dc<<1)|(dp>>63);
            uint64_t p8 = (mc<<1)|(mp>>63);
            uint64_t p9 = (uc<<1)|(up>>63);
            uint64_t qq[8] = {p2,p3,p4,p5,p6,p7,p8,p9};
            uint64_t n0,n1,n2,n3; sum8(qq,n0,n1,n2,n3);
            uint64_t condB = (n1|n2|n3) & ~(n3 | (n2&n1&n0));
            uint64_t tq[8];
            #pragma unroll
            for (int k = 0; k < 8; ++k) tq[k] = ~qq[k] & qq[(k+1)&7];
            uint64_t t0,t1,t2,t3; sum8(tq,t0,t1,t2,t3);
            uint64_t trans1 = t0 & ~(t1|t2|t3);
            uint64_t cond2 = (step & 1) ? (~(p2&p4&p8) & ~(p2&p6&p8))
                                        : (~(p2&p4&p6) & ~(p4&p6&p8));
            nxt[o] = mc & ~(condB & trans1 & cond2);
        }
        __syncthreads();
        uint64_t* t = cur; cur = nxt; nxt = t;
    }
    // Endpoint C (all 8 neighbors set) into B, rows lr 16..153.
    for (int i = tid; i < 138*WPR; i += 512) {
        int lr = (i >> 3) + 16, c = i & 7;
        int o = (lr+1)*LP + c + 1;
        uint64_t up = cur[o-LP-1], uc = cur[o-LP], un = cur[o-LP+1];
        uint64_t mp = cur[o-1],    mc = cur[o],    mn = cur[o+1];
        uint64_t dp = cur[o+LP-1], dc = cur[o+LP], dn = cur[o+LP+1];
        uint64_t p3 = (uc>>1)|(un<<63);
        uint64_t p4 = (mc>>1)|(mn<<63);
        uint64_t p5 = (dc>>1)|(dn<<63);
        uint64_t p7 = (dc<<1)|(dp>>63);
        uint64_t p8 = (mc<<1)|(mp>>63);
        uint64_t p9 = (uc<<1)|(up>>63);
        B[o] = uc & p3 & p4 & p5 & dc & p7 & p8 & p9;
    }
    __syncthreads();
    // Phase A: horizontal 9-window sums (center included) -> 4 bit-planes
    for (int i = tid; i < 136*WPR; i += 512) {
        int hr = i >> 3, c = i & 7;
        int o = (hr+18)*LP + c + 1;                    // lr = hr+17
        uint64_t mp = B[o-1], mc = B[o], mn = B[o+1];
        uint64_t m[8];
        m[0] = (mc>>1)|(mn<<63); m[1] = (mc>>2)|(mn<<62);
        m[2] = (mc>>3)|(mn<<61); m[3] = (mc>>4)|(mn<<60);
        m[4] = (mc<<1)|(mp>>63); m[5] = (mc<<2)|(mp>>62);
        m[6] = (mc<<3)|(mp>>61); m[7] = (mc<<4)|(mp>>60);
        uint64_t b0,b1,b2,b3; sum8(m,b0,b1,b2,b3);
        uint64_t inc = mc;
        uint64_t s0 = b0 ^ inc; inc &= b0;
        uint64_t s1 = b1 ^ inc; inc &= b1;
        uint64_t s2 = b2 ^ inc; inc &= b2;
        uint64_t s3 = b3 ^ inc;
        Hs[0*1088 + i] = s0; Hs[1*1088 + i] = s1;
        Hs[2*1088 + i] = s2; Hs[3*1088 + i] = s3;
    }
    __syncthreads();
    // Phase B: vertical 9-row sums -> 7 bit-planes, minus center C bit.
    for (int i = tid; i < 128*WPR; i += 512) {
        int orr = i >> 3, c = i & 7;
        uint64_t w[7];
        int h0 = orr*WPR + c;
        w[0] = Hs[0*1088 + h0]; w[1] = Hs[1*1088 + h0];
        w[2] = Hs[2*1088 + h0]; w[3] = Hs[3*1088 + h0];
        w[4] = 0; w[5] = 0; w[6] = 0;
        #pragma unroll
        for (int d = 1; d < 9; ++d) {
            int hh = (orr+d)*WPR + c;
            acc74(w, Hs[0*1088+hh], Hs[1*1088+hh], Hs[2*1088+hh], Hs[3*1088+hh]);
        }
        uint64_t cb = B[(orr+HALO+1)*LP + c + 1];
        #pragma unroll
        for (int j = 0; j < 7; ++j) {
            uint64_t t = w[j];
            w[j] = t ^ cb;
            cb &= ~t;
        }
        size_t widx = ((size_t)s*HH + base + orr)*WPR + c;
        #pragma unroll
        for (int j = 0; j < 7; ++j) wp[j*PLANE + widx] = w[j];
    }
}

// sparse final: one thread per 64-pixel word; skip words with W==0 entirely.
__global__ __launch_bounds__(256) void k_final(const float* __restrict__ x,
                        const float* __restrict__ y,
                        const uint64_t* __restrict__ wp,
                        double* __restrict__ partials) {
    int widx = blockIdx.x * blockDim.x + threadIdx.x;  // 262144 threads, one word each
    double acc = 0.0;
    uint64_t w[7];
    uint64_t any = 0;
    #pragma unroll
    for (int j = 0; j < 7; ++j) { w[j] = wp[j*PLANE + widx]; any |= w[j]; }
    if (any) {
        int c  = widx & 7;
        int r  = (widx >> 3) & (HH-1);
        int sl = widx >> 12;
        size_t pix0 = (((size_t)sl*HH + r) << 9) + ((size_t)c << 6);
        uint64_t rem = any;
        while (rem) {
            int bit = __builtin_ctzll(rem);
            rem &= rem - 1;
            int wv = 0;
            #pragma unroll
            for (int j = 0; j < 7; ++j) wv |= (int)((w[j] >> bit) & 1ULL) << j;
            size_t idx = pix0 + bit;
            float lx = x[idx], ly = y[idx];
            float loss = fmaxf(lx, 0.f) - lx*ly + log1pf(expf(-fabsf(lx)));
            acc += (double)(loss * (60.0f * (float)wv));
        }
    }
    __shared__ double sdata[256];
    sdata[threadIdx.x] = acc;
    __syncthreads();
    for (int s2 = 128; s2 > 0; s2 >>= 1) {
        if (threadIdx.x < s2) sdata[threadIdx.x] += sdata[threadIdx.x + s2];
        __syncthreads();
    }
    if (threadIdx.x == 0) partials[blockIdx.x] = sdata[0];
}

__global__ void k_reduce(const double* __restrict__ partials, float* __restrict__ out,
                         int nparts) {
    __shared__ double sdata[256];
    double a = 0.0;
    for (int i = threadIdx.x; i < nparts; i += 256) a += partials[i];
    sdata[threadIdx.x] = a;
    __syncthreads();
    for (int s2 = 128; s2 > 0; s2 >>= 1) {
        if (threadIdx.x < s2) sdata[threadIdx.x] += sdata[threadIdx.x + s2];
        __syncthreads();
    }
    if (threadIdx.x == 0) out[0] = (float)(sdata[0] / (double)NELEM);
}

// ---- launch ------------------------------------------------------------------

extern "C" void kernel_launch(void* const* d_in, const int* in_sizes, int n_in,
                              void* d_out, int out_size, void* d_ws, size_t ws_size,
                              hipStream_t stream) {
    const float* x = (const float*)d_in[0];
    const float* y = (const float*)d_in[1];
    char* ws = (char*)d_ws;
    uint64_t* packA    = (uint64_t*)(ws);              // 2 MB
    uint64_t* wplanes  = (uint64_t*)(ws + (2u<<20));   // 7 x 2 MB
    double*   partials = (double*)  (ws + (17u<<20));  // 8 KB

    k_binarize<<<4096, 256, 0, stream>>>(x, packA);
    k_thin_wmap<<<256, 512, 0, stream>>>(packA, wplanes);
    k_final<<<1024, 256, 0, stream>>>(x, y, wplanes, partials);
    k_reduce<<<1, 256, 0, stream>>>(partials, (float*)d_out, 1024);
}

// Round 4
// 31.655 us; speedup vs baseline: 6.0733x; 2.1190x over previous
//
#include <hip/hip_runtime.h>
#include <cstdint>

#define HH 512
#define WW 512
#define NBATCH 16
#define NPRED 4
#define WPR 8                        // 64-bit words per row
#define NELEM (NBATCH*NPRED*HH*WW)   // 16,777,216
#define HALO 21
#define OUTR 64                      // output rows per block
#define NRTOT (OUTR + 2*HALO)        // 106 LDS data rows
#define LP (WPR+2)                   // padded LDS row stride
#define NBLK 512                     // 64 slices * 8 blocks
#define NTHR 256

// ---- bit-sliced helpers -----------------------------------------------------

static __device__ __forceinline__ void fadd(uint64_t a, uint64_t b, uint64_t ci,
                                            uint64_t& s, uint64_t& co) {
    uint64_t x = a ^ b;
    s  = x ^ ci;
    co = (a & b) | (ci & x);
}

static __device__ __forceinline__ void faddio(uint64_t& a, uint64_t b, uint64_t& c) {
    uint64_t x = a ^ b;
    uint64_t s = x ^ c;
    c = (a & b) | (c & x);
    a = s;
}

static __device__ __forceinline__ void sum8(const uint64_t q[8],
                                            uint64_t& b0, uint64_t& b1,
                                            uint64_t& b2, uint64_t& b3) {
    uint64_t s0,c0,s1,c1,s2,c2;
    fadd(q[0],q[1],q[2], s0,c0);
    fadd(q[3],q[4],q[5], s1,c1);
    s2 = q[6] ^ q[7]; c2 = q[6] & q[7];
    uint64_t ca; fadd(s0,s1,s2, b0, ca);
    uint64_t t, cb; fadd(c0,c1,c2, t, cb);
    b1 = t ^ ca; uint64_t cc = t & ca;
    b2 = cb ^ cc; b3 = cb & cc;
}

// w[0..6] += 4-bit number (b0..b3); max 81, no overflow past bit 6
static __device__ __forceinline__ void acc74(uint64_t w[7], uint64_t b0, uint64_t b1,
                                             uint64_t b2, uint64_t b3) {
    uint64_t c;
    { uint64_t x = w[0] ^ b0; c = w[0] & b0; w[0] = x; }
    faddio(w[1], b1, c);
    faddio(w[2], b2, c);
    faddio(w[3], b3, c);
    { uint64_t x = w[4] ^ c; c = w[4] & c; w[4] = x; }
    { uint64_t x = w[5] ^ c; c = w[5] & c; w[5] = x; }
    w[6] ^= c;
}

// ---- kernels ----------------------------------------------------------------

// softmax over batch axis, threshold 0.5, pack bits (one thread per (p,h,w))
__global__ void k_binarize(const float* __restrict__ x, uint64_t* __restrict__ pack) {
    int tid = blockIdx.x * blockDim.x + threadIdx.x;   // 4*512*512 threads
    int w = tid & (WW-1);
    int h = (tid >> 9) & (HH-1);
    int p = tid >> 18;
    int lane = threadIdx.x & 63;
    float v[NBATCH], e[NBATCH];
    float m = -3.4e38f;
    int base = (p*HH + h)*WW + w;
    #pragma unroll
    for (int b = 0; b < NBATCH; ++b) {
        v[b] = x[(size_t)b*(NPRED*HH*WW) + base];
        m = fmaxf(m, v[b]);
    }
    float S = 0.f;
    #pragma unroll
    for (int b = 0; b < NBATCH; ++b) { e[b] = expf(v[b] - m); S += e[b]; }
    float hS = 0.5f * S;
    unsigned long long mymask = 0ULL;
    #pragma unroll
    for (int b = 0; b < NBATCH; ++b) {
        unsigned long long mk = __ballot(e[b] >= hS);
        if (lane == b) mymask = mk;
    }
    if (lane < NBATCH) {
        int slice = lane * NPRED + p;                  // b*Np + p
        pack[((size_t)slice*HH + h)*WPR + (w >> 6)] = mymask;
    }
}

// fused: 16 Zhang-Suen substeps (early-exit on convergence) + endpoint C +
// 9x9-minus-center weight + sparse loss evaluation -> per-block double partial.
__global__ __launch_bounds__(NTHR) void k_thin_wmap(const uint64_t* __restrict__ pack,
                                                    const float* __restrict__ x,
                                                    const float* __restrict__ y,
                                                    double* __restrict__ partials) {
    __shared__ uint64_t A[(NRTOT+2)*LP];
    __shared__ uint64_t B[(NRTOT+2)*LP];
    __shared__ uint64_t Hs[4*72*WPR];                  // horizontal-sum planes
    __shared__ int chg[16];
    __shared__ int cflag;
    __shared__ double sdata[NTHR];

    const int s    = blockIdx.x >> 3;
    const int base = (blockIdx.x & 7) << 6;
    const int R0   = base - HALO;
    const int tid  = threadIdx.x;

    for (int i = tid; i < (NRTOT+2)*LP; i += NTHR) { A[i] = 0; B[i] = 0; }
    if (tid < 16) chg[tid] = 0;
    if (tid == 0) cflag = 0;
    __syncthreads();
    for (int i = tid; i < NRTOT*WPR; i += NTHR) {
        int lr = i >> 3, c = i & 7;
        int r = R0 + lr;
        if ((unsigned)r < (unsigned)HH)
            A[(lr+1)*LP + c + 1] = pack[((size_t)s*HH + r)*WPR + c];
    }
    __syncthreads();

    uint64_t* cur = A; uint64_t* nxt = B;
    int stable = 0;
    for (int step = 0; step < 16; ++step) {
        if (stable >= 2) break;                        // uniform across block
        bool mych = false;
        for (int i = tid; i < NRTOT*WPR; i += NTHR) {
            int lr = i >> 3, c = i & 7;
            int o = (lr+1)*LP + c + 1;
            uint64_t up = cur[o-LP-1], uc = cur[o-LP], un = cur[o-LP+1];
            uint64_t mp = cur[o-1],    mc = cur[o],    mn = cur[o+1];
            uint64_t dp = cur[o+LP-1], dc = cur[o+LP], dn = cur[o+LP+1];
            uint64_t p2 = uc;
            uint64_t p3 = (uc>>1)|(un<<63);
            uint64_t p4 = (mc>>1)|(mn<<63);
            uint64_t p5 = (dc>>1)|(dn<<63);
            uint64_t p6 = dc;
            uint64_t p7 = (dc<<1)|(dp>>63);
            uint64_t p8 = (mc<<1)|(mp>>63);
            uint64_t p9 = (uc<<1)|(up>>63);
            uint64_t qq[8] = {p2,p3,p4,p5,p6,p7,p8,p9};
            uint64_t n0,n1,n2,n3; sum8(qq,n0,n1,n2,n3);
            uint64_t condB = (n1|n2|n3) & ~(n3 | (n2&n1&n0));
            uint64_t tq[8];
            #pragma unroll
            for (int k = 0; k < 8; ++k) tq[k] = ~qq[k] & qq[(k+1)&7];
            uint64_t t0,t1,t2,t3; sum8(tq,t0,t1,t2,t3);
            uint64_t trans1 = t0 & ~(t1|t2|t3);
            uint64_t cond2 = (step & 1) ? (~(p2&p4&p8) & ~(p2&p6&p8))
                                        : (~(p2&p4&p6) & ~(p4&p6&p8));
            uint64_t nv = mc & ~(condB & trans1 & cond2);
            nxt[o] = nv;
            mych |= (nv != mc);
        }
        if (mych) chg[step] = 1;
        __syncthreads();
        stable = chg[step] ? 0 : stable + 1;
        uint64_t* t = cur; cur = nxt; nxt = t;
    }

    // Endpoint C (all 8 neighbors set) from skeleton (cur) into Cb (nxt),
    // rows lr 17..88 (valid after 16 substeps).
    uint64_t* Cb = nxt;
    for (int i = tid; i < 72*WPR; i += NTHR) {
        int lr = (i >> 3) + 17, c = i & 7;
        int o = (lr+1)*LP + c + 1;
        uint64_t up = cur[o-LP-1], uc = cur[o-LP], un = cur[o-LP+1];
        uint64_t mp = cur[o-1],    mc = cur[o],    mn = cur[o+1];
        uint64_t dp = cur[o+LP-1], dc = cur[o+LP], dn = cur[o+LP+1];
        uint64_t p3 = (uc>>1)|(un<<63);
        uint64_t p4 = (mc>>1)|(mn<<63);
        uint64_t p5 = (dc>>1)|(dn<<63);
        uint64_t p7 = (dc<<1)|(dp>>63);
        uint64_t p8 = (mc<<1)|(mp>>63);
        uint64_t p9 = (uc<<1)|(up>>63);
        uint64_t cv = uc & p3 & p4 & p5 & dc & p7 & p8 & p9;
        Cb[o] = cv;
        if (cv) cflag = 1;
    }
    __syncthreads();

    if (!cflag) {                                      // uniform: weight map is 0
        if (tid == 0) partials[blockIdx.x] = 0.0;
        return;
    }

    // Phase A: horizontal 9-window sums (center included) -> 4 bit-planes
    for (int i = tid; i < 72*WPR; i += NTHR) {
        int hr = i >> 3, c = i & 7;
        int o = (hr+18)*LP + c + 1;                    // lr = hr+17
        uint64_t mp = Cb[o-1], mc = Cb[o], mn = Cb[o+1];
        uint64_t m[8];
        m[0] = (mc>>1)|(mn<<63); m[1] = (mc>>2)|(mn<<62);
        m[2] = (mc>>3)|(mn<<61); m[3] = (mc>>4)|(mn<<60);
        m[4] = (mc<<1)|(mp>>63); m[5] = (mc<<2)|(mp>>62);
        m[6] = (mc<<3)|(mp>>61); m[7] = (mc<<4)|(mp>>60);
        uint64_t b0,b1,b2,b3; sum8(m,b0,b1,b2,b3);
        uint64_t inc = mc;
        uint64_t s0 = b0 ^ inc; inc &= b0;
        uint64_t s1 = b1 ^ inc; inc &= b1;
        uint64_t s2 = b2 ^ inc; inc &= b2;
        uint64_t s3 = b3 ^ inc;
        Hs[0*576 + i] = s0; Hs[1*576 + i] = s1;
        Hs[2*576 + i] = s2; Hs[3*576 + i] = s3;
    }
    __syncthreads();

    // Phase B: vertical 9-row sums -> 7-bit weight, minus center C bit,
    // then sparse loss evaluation.
    double acc = 0.0;
    for (int i = tid; i < OUTR*WPR; i += NTHR) {
        int orr = i >> 3, c = i & 7;
        uint64_t w[7];
        int h0 = orr*WPR + c;
        w[0] = Hs[0*576 + h0]; w[1] = Hs[1*576 + h0];
        w[2] = Hs[2*576 + h0]; w[3] = Hs[3*576 + h0];
        w[4] = 0; w[5] = 0; w[6] = 0;
        #pragma unroll
        for (int d = 1; d < 9; ++d) {
            int hh = (orr+d)*WPR + c;
            acc74(w, Hs[0*576+hh], Hs[1*576+hh], Hs[2*576+hh], Hs[3*576+hh]);
        }
        uint64_t cb = Cb[(orr+HALO+1)*LP + c + 1];
        #pragma unroll
        for (int j = 0; j < 7; ++j) {
            uint64_t t = w[j];
            w[j] = t ^ cb;
            cb &= ~t;
        }
        uint64_t any = w[0]|w[1]|w[2]|w[3]|w[4]|w[5]|w[6];
        if (any) {
            size_t pix0 = ((size_t)s*HH + (base + orr))*WW + ((size_t)c << 6);
            uint64_t rem = any;
            while (rem) {
                int bit = __builtin_ctzll(rem);
                rem &= rem - 1;
                int wv = 0;
                #pragma unroll
                for (int j = 0; j < 7; ++j) wv |= (int)((w[j] >> bit) & 1ULL) << j;
                size_t idx = pix0 + bit;
                float lx = x[idx], ly = y[idx];
                float loss = fmaxf(lx, 0.f) - lx*ly + log1pf(expf(-fabsf(lx)));
                acc += (double)(loss * (60.0f * (float)wv));
            }
        }
    }
    sdata[tid] = acc;
    __syncthreads();
    for (int s2 = NTHR/2; s2 > 0; s2 >>= 1) {
        if (tid < s2) sdata[tid] += sdata[tid + s2];
        __syncthreads();
    }
    if (tid == 0) partials[blockIdx.x] = sdata[0];
}

__global__ void k_reduce(const double* __restrict__ partials, float* __restrict__ out,
                         int nparts) {
    __shared__ double sdata[256];
    double a = 0.0;
    for (int i = threadIdx.x; i < nparts; i += 256) a += partials[i];
    sdata[threadIdx.x] = a;
    __syncthreads();
    for (int s2 = 128; s2 > 0; s2 >>= 1) {
        if (threadIdx.x < s2) sdata[threadIdx.x] += sdata[threadIdx.x + s2];
        __syncthreads();
    }
    if (threadIdx.x == 0) out[0] = (float)(sdata[0] / (double)NELEM);
}

// ---- launch ------------------------------------------------------------------

extern "C" void kernel_launch(void* const* d_in, const int* in_sizes, int n_in,
                              void* d_out, int out_size, void* d_ws, size_t ws_size,
                              hipStream_t stream) {
    const float* x = (const float*)d_in[0];
    const float* y = (const float*)d_in[1];
    char* ws = (char*)d_ws;
    uint64_t* packA    = (uint64_t*)(ws);              // 2 MB
    double*   partials = (double*)  (ws + (2u<<20));   // 4 KB

    k_binarize<<<4096, 256, 0, stream>>>(x, packA);
    k_thin_wmap<<<NBLK, NTHR, 0, stream>>>(packA, x, y, partials);
    k_reduce<<<1, 256, 0, stream>>>(partials, (float*)d_out, NBLK);
}